// Round 6
// baseline (111.942 us; speedup 1.0000x reference)
//
#include <hip/hip_runtime.h>

#define B_SZ  4
#define N_TOK 4096   // H*W
#define CH    256
#define CR    32
#define SEG   256    // keys per wave (split-K segment), 16 waves/block
#define KT    32     // keys per iteration
#define NITER (SEG / KT)
#define LOG2E 1.44269504f

typedef __attribute__((ext_vector_type(8))) short bf16x8;  // 8 bf16 = 4 VGPRs
typedef __attribute__((ext_vector_type(4))) float f32x4;

__device__ inline ushort f2bf(float x) {           // RNE fp32->bf16
    uint u = __float_as_uint(x);
    u += 0x7fff + ((u >> 16) & 1);
    return (ushort)(u >> 16);
}
__device__ inline uint pk2bf(float a, float b) {   // [bf16(b)|bf16(a)], truncate
    return __builtin_amdgcn_perm(__float_as_uint(b), __float_as_uint(a), 0x07060302);
}
__device__ inline float fast_exp2(float x) {       // raw v_exp_f32 (1 instr) when available
#if __has_builtin(__builtin_amdgcn_exp2f)
    return __builtin_amdgcn_exp2f(x);
#else
    return exp2f(x);
#endif
}

// exp2 both score frags of one 16-query group, pack bf16, write the LDS-transpose row.
// Returns the partial rowsum contribution.
__device__ inline float exp_pack_row(const f32x4 s0, const f32x4 s1, ushort* rp, int Q) {
    float p0 = fast_exp2(s0[0]), p1 = fast_exp2(s0[1]);
    float p2 = fast_exp2(s0[2]), p3 = fast_exp2(s0[3]);
    float s4 = ((p0 + p1) + (p2 + p3));
    uint2 w; w.x = pk2bf(p0, p1); w.y = pk2bf(p2, p3);
    *(uint2*)(rp + Q * 4) = w;
    p0 = fast_exp2(s1[0]); p1 = fast_exp2(s1[1]);
    p2 = fast_exp2(s1[2]); p3 = fast_exp2(s1[3]);
    s4 += ((p0 + p1) + (p2 + p3));
    w.x = pk2bf(p0, p1); w.y = pk2bf(p2, p3);
    *(uint2*)(rp + 16 + Q * 4) = w;
    return s4;
}

// ---------- Kernel A: MFMA projections. Self-stages Wf/Wg/Wh (no prep kernel).
// Each block: 256 thr = 4 waves; wave wv owns 16 tokens x full K=256. g scaled by log2(e).
// R12: h^T output is written in 32x32 key-tiles: ht[b][tok/32][ch][tok&31], so attn's
// B-frag loads are fully coalesced (1 KB contiguous per instruction). ----------
__global__ __launch_bounds__(256) void proj_kernel(
    const float* __restrict__ x,
    const float* __restrict__ Wf, const float* __restrict__ Wg, const float* __restrict__ Wh,
    const float* __restrict__ bf_, const float* __restrict__ bg, const float* __restrict__ bh,
    ushort* __restrict__ fo, ushort* __restrict__ go, ushort* __restrict__ hto)
{
    __shared__ ushort wst[3][32][264];   // W^T bf16, row stride 528 B
    int t = threadIdx.x;

    {   // stage: thread t = K-row t; coalesced float4 reads, contiguous ds writes
        float4 r4[8];
        const float* rf = (const float*)&r4[0];
        #pragma unroll
        for (int q4 = 0; q4 < 8; ++q4) r4[q4] = *(const float4*)(Wf + (size_t)t * CR + q4 * 4);
        #pragma unroll
        for (int j = 0; j < 32; ++j) wst[0][j][t] = f2bf(rf[j]);
        #pragma unroll
        for (int q4 = 0; q4 < 8; ++q4) r4[q4] = *(const float4*)(Wg + (size_t)t * CR + q4 * 4);
        #pragma unroll
        for (int j = 0; j < 32; ++j) wst[1][j][t] = f2bf(rf[j]);
        #pragma unroll
        for (int q4 = 0; q4 < 8; ++q4) r4[q4] = *(const float4*)(Wh + (size_t)t * CR + q4 * 4);
        #pragma unroll
        for (int j = 0; j < 32; ++j) wst[2][j][t] = f2bf(rf[j]);
    }
    __syncthreads();

    int wv = t >> 6, L = t & 63, nl = L & 15, Q = L >> 4;
    int row_t = blockIdx.x * 64 + wv * 16;
    int b = row_t >> 12, tok0 = row_t & 4095;

    const float* xrow = x + (size_t)(row_t + nl) * CH;
    f32x4 A[6];
    #pragma unroll
    for (int i = 0; i < 6; ++i) A[i] = (f32x4){0.f, 0.f, 0.f, 0.f};

    #pragma unroll
    for (int kk = 0; kk < 8; ++kk) {
        int off = kk * 32 + Q * 8;
        float4 lo = *(const float4*)(xrow + off);
        float4 hi = *(const float4*)(xrow + off + 4);
        bf16x8 xa;
        xa[0] = (short)f2bf(lo.x); xa[1] = (short)f2bf(lo.y);
        xa[2] = (short)f2bf(lo.z); xa[3] = (short)f2bf(lo.w);
        xa[4] = (short)f2bf(hi.x); xa[5] = (short)f2bf(hi.y);
        xa[6] = (short)f2bf(hi.z); xa[7] = (short)f2bf(hi.w);

        bf16x8 wf0 = *(const bf16x8*)&wst[0][nl][off];
        bf16x8 wf1 = *(const bf16x8*)&wst[0][16 + nl][off];
        bf16x8 wg0 = *(const bf16x8*)&wst[1][nl][off];
        bf16x8 wg1 = *(const bf16x8*)&wst[1][16 + nl][off];
        bf16x8 wh0 = *(const bf16x8*)&wst[2][nl][off];
        bf16x8 wh1 = *(const bf16x8*)&wst[2][16 + nl][off];

        A[0] = __builtin_amdgcn_mfma_f32_16x16x32_bf16(xa, wf0, A[0], 0, 0, 0);
        A[1] = __builtin_amdgcn_mfma_f32_16x16x32_bf16(xa, wf1, A[1], 0, 0, 0);
        A[2] = __builtin_amdgcn_mfma_f32_16x16x32_bf16(xa, wg0, A[2], 0, 0, 0);
        A[3] = __builtin_amdgcn_mfma_f32_16x16x32_bf16(xa, wg1, A[3], 0, 0, 0);
        A[4] = __builtin_amdgcn_mfma_f32_16x16x32_bf16(wh0, xa, A[4], 0, 0, 0);  // h^T
        A[5] = __builtin_amdgcn_mfma_f32_16x16x32_bf16(wh1, xa, A[5], 0, 0, 0);
    }

    float bF0 = bf_[nl], bF1 = bf_[16 + nl];
    float bG0 = bg[nl] * LOG2E, bG1 = bg[16 + nl] * LOG2E;
    #pragma unroll
    for (int r = 0; r < 4; ++r) {
        size_t ro = (size_t)(row_t + Q * 4 + r) * CR;
        fo[ro + nl]      = f2bf(A[0][r] + bF0);
        fo[ro + 16 + nl] = f2bf(A[1][r] + bF1);
        go[ro + nl]      = f2bf(fmaf(A[2][r], LOG2E, bG0));
        go[ro + 16 + nl] = f2bf(fmaf(A[3][r], LOG2E, bG1));
    }
    // tiled h^T store: ht[b][tok/32][ch][tok&31]; tok = tok0 + nl (nl<16, so tile is
    // constant per wave: tile = tok0>>5, key-in-tile = (tok0&31)+nl)
    ushort* hb = hto + (size_t)b * CR * N_TOK + (size_t)(tok0 >> 5) * (CR * 32) + (tok0 & 31) + nl;
    #pragma unroll
    for (int r = 0; r < 4; ++r) {
        int ch = Q * 4 + r;
        hb[ch * 32]        = f2bf(A[4][r] + bh[ch]);
        hb[(16 + ch) * 32] = f2bf(A[5][r] + bh[16 + ch]);
    }
}

// ---------- Kernel B: attention — R12: R11 structure (64 q/block, 16 waves x 256-key split-K,
// KT=32, XCD-bijective swizzle, intra-iteration modulo schedule) +
// (a) tiled ht layout -> both bh loads are contiguous 1 KB per instruction,
// (b) s_setprio(1) around the pure-MFMA PV quads (barrier-free waves: T5-positive regime). ----------
__global__ __launch_bounds__(1024, 4) void attn_kernel(
    const ushort* __restrict__ f, const ushort* __restrict__ g,
    const ushort* __restrict__ ht, const float* __restrict__ Wv,
    const float* __restrict__ bv, const float* __restrict__ gamma,
    const float* __restrict__ x, float* __restrict__ out)
{
    // 81920 B shared, aliased:
    //   K-loop:  pls[16][64][40] ushort (row stride 80 B: 16B-aligned b128 reads, <=2-way banks)
    //   post:    obuf[8][64][33] f32 (67584) + lbuf[16][64] f32 (4096 @67584) + oc[64][48] (6144 @71680)
    __shared__ unsigned long long smem_raw[81920 / 8];
    ushort (*pls)[64][40]  = (ushort (*)[64][40])smem_raw;
    float  (*obuf)[64][33] = (float (*)[64][33])smem_raw;
    float  (*lbuf)[64]     = (float (*)[64])((char*)smem_raw + 67584);
    ushort (*oc)[48]       = (ushort (*)[48])((char*)smem_raw + 71680);

    int t  = threadIdx.x;
    int wv = t >> 6;           // 0..15
    int L  = t & 63;
    int nl = L & 15;
    int Q  = L >> 4;
    // XCD swizzle: 256 blocks = 8 XCDs x 32 (bijective); per-XCD f/ht set = 1 batch = 512 KB.
    int bid = blockIdx.x;
    int swz = (bid & 7) * 32 + (bid >> 3);
    int b  = swz >> 6;
    int q0 = (swz & 63) * 64;

    const ushort* fb  = f  + (size_t)b * N_TOK * CR;
    const ushort* htb = ht + (size_t)b * CR * N_TOK;

    bf16x8 gB[4];
    #pragma unroll
    for (int qh = 0; qh < 4; ++qh)
        gB[qh] = *(const bf16x8*)(g + ((size_t)b * N_TOK + q0 + qh * 16 + nl) * CR + Q * 8);

    f32x4 acc[4][2];
    #pragma unroll
    for (int i = 0; i < 4; ++i) { acc[i][0] = (f32x4){0,0,0,0}; acc[i][1] = (f32x4){0,0,0,0}; }
    const f32x4 zf = {0,0,0,0};
    float ls0 = 0.f, ls1 = 0.f, ls2 = 0.f, ls3 = 0.f;

    int key0 = wv * SEG;
    bf16x8 Ac0 = *(const bf16x8*)(fb + (size_t)(key0 +      nl) * CR + Q * 8);
    bf16x8 Ac1 = *(const bf16x8*)(fb + (size_t)(key0 + 16 + nl) * CR + Q * 8);

    #pragma unroll 2
    for (int it = 0; it < NITER; ++it) {
        int kc = key0 + it * KT;
        // ht B-frags from the 32x32 key-tile at kc: base + ch*32 + kin.
        // bh0 = bytes [0,1024) of the tile, bh1 = [1024,2048) — fully coalesced.
        const ushort* hk = htb + (size_t)kc * CR + nl * 32 + Q * 8;
        bf16x8 bh0 = *(const bf16x8*)(hk);
        bf16x8 bh1 = *(const bf16x8*)(hk + 512);
        // next iteration's f A-frags (kept valid on last iter)
        int kn = key0 + ((it + 1 < NITER) ? it + 1 : 0) * KT;
        bf16x8 An0 = *(const bf16x8*)(fb + (size_t)(kn +      nl) * CR + Q * 8);
        bf16x8 An1 = *(const bf16x8*)(fb + (size_t)(kn + 16 + nl) * CR + Q * 8);

        f32x4 t0, t1;
        // qh0 / qh1: QK + exp2 + pack + transpose-write
        t0 = __builtin_amdgcn_mfma_f32_16x16x32_bf16(Ac0, gB[0], zf, 0, 0, 0);
        t1 = __builtin_amdgcn_mfma_f32_16x16x32_bf16(Ac1, gB[0], zf, 0, 0, 0);
        ls0 += exp_pack_row(t0, t1, &pls[wv][nl][0], Q);
        t0 = __builtin_amdgcn_mfma_f32_16x16x32_bf16(Ac0, gB[1], zf, 0, 0, 0);
        t1 = __builtin_amdgcn_mfma_f32_16x16x32_bf16(Ac1, gB[1], zf, 0, 0, 0);
        ls1 += exp_pack_row(t0, t1, &pls[wv][16 + nl][0], Q);
        // issue P-readbacks for qh0/qh1 (rows already written; wave-private DS is in-order)
        bf16x8 aP0 = *(const bf16x8*)&pls[wv][     nl][Q * 8];
        bf16x8 aP1 = *(const bf16x8*)&pls[wv][16 + nl][Q * 8];
        // qh2 covers aP0/aP1 DS latency
        t0 = __builtin_amdgcn_mfma_f32_16x16x32_bf16(Ac0, gB[2], zf, 0, 0, 0);
        t1 = __builtin_amdgcn_mfma_f32_16x16x32_bf16(Ac1, gB[2], zf, 0, 0, 0);
        ls2 += exp_pack_row(t0, t1, &pls[wv][32 + nl][0], Q);
        bf16x8 aP2 = *(const bf16x8*)&pls[wv][32 + nl][Q * 8];
        __builtin_amdgcn_s_setprio(1);
        acc[0][0] = __builtin_amdgcn_mfma_f32_16x16x32_bf16(aP0, bh0, acc[0][0], 0, 0, 0);
        acc[0][1] = __builtin_amdgcn_mfma_f32_16x16x32_bf16(aP0, bh1, acc[0][1], 0, 0, 0);
        acc[1][0] = __builtin_amdgcn_mfma_f32_16x16x32_bf16(aP1, bh0, acc[1][0], 0, 0, 0);
        acc[1][1] = __builtin_amdgcn_mfma_f32_16x16x32_bf16(aP1, bh1, acc[1][1], 0, 0, 0);
        __builtin_amdgcn_s_setprio(0);
        // qh3 covers aP2 DS latency
        t0 = __builtin_amdgcn_mfma_f32_16x16x32_bf16(Ac0, gB[3], zf, 0, 0, 0);
        t1 = __builtin_amdgcn_mfma_f32_16x16x32_bf16(Ac1, gB[3], zf, 0, 0, 0);
        ls3 += exp_pack_row(t0, t1, &pls[wv][48 + nl][0], Q);
        bf16x8 aP3 = *(const bf16x8*)&pls[wv][48 + nl][Q * 8];
        __builtin_amdgcn_s_setprio(1);
        acc[2][0] = __builtin_amdgcn_mfma_f32_16x16x32_bf16(aP2, bh0, acc[2][0], 0, 0, 0);
        acc[2][1] = __builtin_amdgcn_mfma_f32_16x16x32_bf16(aP2, bh1, acc[2][1], 0, 0, 0);
        acc[3][0] = __builtin_amdgcn_mfma_f32_16x16x32_bf16(aP3, bh0, acc[3][0], 0, 0, 0);
        acc[3][1] = __builtin_amdgcn_mfma_f32_16x16x32_bf16(aP3, bh1, acc[3][1], 0, 0, 0);
        __builtin_amdgcn_s_setprio(0);

        Ac0 = An0; Ac1 = An1;
    }

    // reduce lsum across the 4 Q-quarters (lanes nl, nl+16, nl+32, nl+48)
    ls0 += __shfl_xor(ls0, 16); ls0 += __shfl_xor(ls0, 32);
    ls1 += __shfl_xor(ls1, 16); ls1 += __shfl_xor(ls1, 32);
    ls2 += __shfl_xor(ls2, 16); ls2 += __shfl_xor(ls2, 32);
    ls3 += __shfl_xor(ls3, 16); ls3 += __shfl_xor(ls3, 32);

    __syncthreads();   // all pls reads done before aliasing as obuf

    // two-stage wave reduction: waves 8..15 spill to LDS; waves 0..7 add in-register
    if (wv >= 8) {
        #pragma unroll
        for (int qh = 0; qh < 4; ++qh)
            #pragma unroll
            for (int r = 0; r < 4; ++r) {
                obuf[wv - 8][qh * 16 + Q * 4 + r][nl]      = acc[qh][0][r];
                obuf[wv - 8][qh * 16 + Q * 4 + r][16 + nl] = acc[qh][1][r];
            }
    }
    if (L < 16) {
        lbuf[wv][     nl] = ls0; lbuf[wv][16 + nl] = ls1;
        lbuf[wv][32 + nl] = ls2; lbuf[wv][48 + nl] = ls3;
    }
    __syncthreads();
    if (wv < 8) {
        #pragma unroll
        for (int qh = 0; qh < 4; ++qh)
            #pragma unroll
            for (int r = 0; r < 4; ++r) {
                obuf[wv][qh * 16 + Q * 4 + r][nl]      += acc[qh][0][r];
                obuf[wv][qh * 16 + Q * 4 + r][16 + nl] += acc[qh][1][r];
            }
    }
    __syncthreads();

    {
        int ch = t & 31, qb = t >> 5;   // 1024 thr -> 2 (q,ch) each
        #pragma unroll
        for (int qq = qb; qq < 64; qq += 32) {
            float s = 0.f, Lq = 0.f;
            #pragma unroll
            for (int w = 0; w < 8; ++w) s += obuf[w][qq][ch];
            #pragma unroll
            for (int w = 0; w < 16; ++w) Lq += lbuf[w][qq];
            oc[qq][ch] = f2bf(s / Lq);
        }
    }
    __syncthreads();

    // fused epilogue: out = gamma*(o@Wv + bv) + x ; wave wv covers out-ch [wv*16, wv*16+16)
    float gm = gamma[0];
    const float* xb = x   + ((size_t)b * N_TOK + q0) * CH;
    float*       ob = out + ((size_t)b * N_TOK + q0) * CH;
    int c = wv * 16 + nl;
    const float* wvp = Wv + c;               // Wv[k][c], k stride CH
    bf16x8 bW;
    #pragma unroll
    for (int j = 0; j < 8; ++j) bW[j] = (short)f2bf(wvp[(size_t)(Q * 8 + j) * CH]);
    float bvc = bv[c];
    #pragma unroll
    for (int qg = 0; qg < 4; ++qg) {
        bf16x8 aO = *(const bf16x8*)&oc[qg * 16 + nl][Q * 8];
        f32x4 d = __builtin_amdgcn_mfma_f32_16x16x32_bf16(aO, bW, zf, 0, 0, 0);
        #pragma unroll
        for (int r = 0; r < 4; ++r) {
            int qa = qg * 16 + Q * 4 + r;
            ob[qa * CH + c] = fmaf(gm, d[r] + bvc, xb[qa * CH + c]);
        }
    }
}

extern "C" void kernel_launch(void* const* d_in, const int* in_sizes, int n_in,
                              void* d_out, int out_size, void* d_ws, size_t ws_size,
                              hipStream_t stream) {
    const float* x     = (const float*)d_in[0];
    const float* Wf    = (const float*)d_in[1];
    const float* bf_   = (const float*)d_in[2];
    const float* Wg    = (const float*)d_in[3];
    const float* bg    = (const float*)d_in[4];
    const float* Wh    = (const float*)d_in[5];
    const float* bh    = (const float*)d_in[6];
    const float* Wv    = (const float*)d_in[7];
    const float* bv    = (const float*)d_in[8];
    const float* gamma = (const float*)d_in[9];
    float* out = (float*)d_out;

    const size_t T = (size_t)B_SZ * N_TOK * CR;     // 524288
    ushort* fo  = (ushort*)d_ws;
    ushort* go  = fo + T;
    ushort* hto = go + T;

    proj_kernel<<<B_SZ * N_TOK / 64, 256, 0, stream>>>(x, Wf, Wg, Wh, bf_, bg, bh, fo, go, hto);
    attn_kernel<<<B_SZ * (N_TOK / 64), 1024, 0, stream>>>(fo, go, hto, Wv, bv, gamma, x, out);
}